// Round 16
// baseline (139.881 us; speedup 1.0000x reference)
//
#include <hip/hip_runtime.h>
#include <hip/hip_bf16.h>

// AttentionBlock B=4, C=128, N=4096.
// gn_wconv (320 blocks — 256 stats + 64 vectorized weight-convert)
// -> qkv_fused (GN finalize+apply + MFMA QKV, transposed tile outputs ->
//               b64 LDS scatter; coalesced stores)
// -> flash_attn (r26: r19 core + TWO-CHUNK SOFTWARE PIPELINE inside each
//                barrier region: QK(A);QK(B) as one MFMA cluster, then
//                SM(A);PV(A);SM(B);PV(B) — cross-chunk ILP hides the serial
//                QK->exp2->pfrag->PV chain. Named static regs (sA/sB/PA/PB),
//                same accumulation order -> bit-identical. K XOR swizzle,
//                V slot involution, DMA 4-buffer ring, -SMAX C-init,
//                l via ones-MFMA.)
// -> merge_out (sum 4 partials * 1/l + MFMA out-proj + bias + residual)
// Ledger: ticket fusion (-97us), coop launch (dropped), 4blk/CU (neutral),
// nt stores (write amplification 16.6->40.4MB) — all falsified and reverted.

#define CH 128
#define SEQ 4096
#define EPSV 1e-5f
// 1/sqrt(128) * log2(e): softmax runs in base-2 domain
#define QSCALE (0.08838834764831845f * 1.4426950408889634f)
// fixed softmax shift: base-2 logits bounded |s2| <~ 15; exp2 overflows only
// at s2-M > 127 -> huge margin. Same M for all j-splits makes merge factors
// collapse to 1/sum(l). Folded into the MFMA accumulator init.
#define SMAX 24.0f

typedef unsigned short u16;
typedef unsigned int u32;
typedef __attribute__((ext_vector_type(8))) short short8;   // 8 bf16 (4 VGPRs)
typedef __attribute__((ext_vector_type(4))) float floatx4;  // MFMA C/D
typedef __attribute__((ext_vector_type(2))) unsigned int u32x2;

__device__ __forceinline__ float bf2f(u16 h) {
    return __uint_as_float(((u32)h) << 16);
}
__device__ __forceinline__ u16 f2bf(float f) {
    u32 u = __float_as_uint(f);
    return (u16)((u + 0x7fffu + ((u >> 16) & 1u)) >> 16);
}
__device__ __forceinline__ u32 pkbf(float a, float b) {   // packed RNE cvt (low=a)
    __hip_bfloat162 h = __float22bfloat162_rn(make_float2(a, b));
    return *(u32*)&h;
}
__device__ __forceinline__ floatx4 mfma16(short8 a, short8 b, floatx4 c) {
    return __builtin_amdgcn_mfma_f32_16x16x32_bf16(a, b, c, 0, 0, 0);
}
// async global->LDS DMA, 16 B/lane. LDS dest must be wave-uniform (HW adds
// lane*16); global source is per-lane (carries the inverse swizzle).
__device__ __forceinline__ void gl_lds16(const u16* g, u16* l) {
    __builtin_amdgcn_global_load_lds(
        (const __attribute__((address_space(1))) unsigned int*)g,
        (__attribute__((address_space(3))) unsigned int*)l,
        16, 0, 0);
}

// Build PV B-fragment (16x16x32) from in-register P, no LDS.
// Source lane (l15, sq) holds P(i, j=jt*16+4*sq+r); P32[jt][h] packs r=2h,2h+1.
// Target lane (l15,q) needs j = 8q + e. Verified r11-r25 (absmax-identical).
__device__ __forceinline__ short8 pfrag(u32 a0, u32 b0, u32 a1, u32 b1) {
    u32x2 s0 = __builtin_amdgcn_permlane32_swap(a0, b0, false, false);
    u32x2 t0 = __builtin_amdgcn_permlane16_swap(s0.x, s0.y, false, false);
    u32x2 s1 = __builtin_amdgcn_permlane32_swap(a1, b1, false, false);
    u32x2 t1 = __builtin_amdgcn_permlane16_swap(s1.x, s1.y, false, false);
    union { u32 u[4]; short8 s; } U;
    U.u[0] = t0.x; U.u[1] = t1.x; U.u[2] = t0.y; U.u[3] = t1.y;
    return U.s;
}

// ---------------- Kernel 1: GN partial stats + weight conversion ---------------
// 320 blocks: 0..255 stats (bg,sub); 256..319 weight convert, 4 elems/thread.
__global__ void gn_wconv(const float* __restrict__ x, float* __restrict__ part,
                         const float* __restrict__ w_qkv, const float* __restrict__ w_out,
                         u16* __restrict__ wq, u16* __restrict__ wo) {
    if (blockIdx.x >= 256) {
        int i = ((blockIdx.x - 256) * 256 + threadIdx.x) * 4;   // 65536 total
        if (i < 49152) {
            float4 v = *(const float4*)(w_qkv + i);
            *(uint2*)(wq + i) = make_uint2(pkbf(v.x, v.y), pkbf(v.z, v.w));
        } else {
            float4 v = *(const float4*)(w_out + (i - 49152));
            *(uint2*)(wo + (i - 49152)) = make_uint2(pkbf(v.x, v.y), pkbf(v.z, v.w));
        }
        return;
    }
    int bg = blockIdx.x >> 3, sub = blockIdx.x & 7;
    const float4* xp = (const float4*)(x + (size_t)bg * 65536 + sub * 8192);
    float s = 0.f, sq = 0.f;
    for (int r = 0; r < 8; ++r) {
        float4 v = xp[threadIdx.x + 256 * r];
        s  += v.x + v.y + v.z + v.w;
        sq += v.x*v.x + v.y*v.y + v.z*v.z + v.w*v.w;
    }
    for (int off = 32; off; off >>= 1) {
        s  += __shfl_down(s, off, 64);
        sq += __shfl_down(sq, off, 64);
    }
    __shared__ float ls[8];
    int wave = threadIdx.x >> 6, lane = threadIdx.x & 63;
    if (lane == 0) { ls[wave*2] = s; ls[wave*2+1] = sq; }
    __syncthreads();
    if (threadIdx.x == 0) {
        float ts = 0.f, tq = 0.f;
        for (int w = 0; w < 4; ++w) { ts += ls[w*2]; tq += ls[w*2+1]; }
        part[blockIdx.x * 2]     = ts;
        part[blockIdx.x * 2 + 1] = tq;
    }
}

// ---------------- Kernel 2: fused GN-apply + MFMA QKV projection ---------------
// 512 blocks = (b, 32-pos chunk). hT[32n][136c] in LDS; wave owns 6 o-tiles.
// Tiles computed TRANSPOSED (operand swap = exact transpose) so each thread's
// 4 C-values are contiguous in the stage buffer -> one ds_write_b64 per tile.
__global__ __launch_bounds__(256, 2) void qkv_fused(
        const float* __restrict__ x, const float* __restrict__ gw,
        const float* __restrict__ gb, const float* __restrict__ part,
        const u16* __restrict__ wq, const float* __restrict__ b_qkv,
        u16* __restrict__ qT, u16* __restrict__ kT, u16* __restrict__ v) {
    __shared__ __align__(16) u16 hT[32 * 136];     // input stage
    __shared__ __align__(16) u16 qbuf[32 * 132];   // [n][c] padded
    __shared__ __align__(16) u16 kbuf[32 * 132];
    __shared__ __align__(16) u16 vbuf[128 * 36];   // [c][n] padded
    __shared__ float cw[128], cb[128];
    int bx = blockIdx.x;            // 512
    int nc = bx & 127, b = bx >> 7;
    int n0 = nc * 32;
    int t = threadIdx.x, w = t >> 6, lane = t & 63;
    int quad = lane >> 4, l15 = lane & 15;

    // finalize GN stats -> per-channel scale/bias
    if (t < 128) {
        int g = t >> 4;
        float s = 0.f, sq = 0.f;
        #pragma unroll
        for (int u = 0; u < 8; ++u) {
            s  += part[((b * 8 + g) * 8 + u) * 2];
            sq += part[((b * 8 + g) * 8 + u) * 2 + 1];
        }
        float mean = s / 65536.f;
        float rstd = rsqrtf(sq / 65536.f - mean * mean + EPSV);
        float wgt = gw[t] * rstd;
        cw[t] = wgt;
        cb[t] = gb[t] - mean * wgt;
    }

    // weight fragments: wave w -> o-tiles w*6 .. w*6+5
    short8 wf[6][4];
    float4 bq4[6];      // q/k tiles: bias for o = T*16 + quad*4 + r
    float  bv[6];       // v tiles: bias for ov = (T-16)*16 + l15
    #pragma unroll
    for (int j = 0; j < 6; ++j) {
        int T = w * 6 + j;
        #pragma unroll
        for (int kt = 0; kt < 4; ++kt)
            wf[j][kt] = *(const short8*)(wq + (T * 16 + l15) * 128 + kt * 32 + quad * 8);
        if (T < 16) bq4[j] = *(const float4*)(b_qkv + T * 16 + quad * 4);
        else        bv[j]  = b_qkv[256 + (T - 16) * 16 + l15];
    }
    __syncthreads();

    // stage GN'd x transposed (32 pos x 128 c); packed converts
    #pragma unroll
    for (int r = 0; r < 4; ++r) {
        int u = r * 256 + t;
        int c = u >> 3, col = (u & 7) * 4;
        float wgt = cw[c], bs = cb[c];
        float4 xv = *(const float4*)(x + ((size_t)(b * 128 + c)) * SEQ + n0 + col);
        u32 p01 = pkbf(fmaf(xv.x, wgt, bs), fmaf(xv.y, wgt, bs));
        u32 p23 = pkbf(fmaf(xv.z, wgt, bs), fmaf(xv.w, wgt, bs));
        hT[(col + 0) * 136 + c] = (u16)p01;
        hT[(col + 1) * 136 + c] = (u16)(p01 >> 16);
        hT[(col + 2) * 136 + c] = (u16)p23;
        hT[(col + 3) * 136 + c] = (u16)(p23 >> 16);
    }
    __syncthreads();

    #pragma unroll
    for (int nt = 0; nt < 2; ++nt) {
        short8 hf[4];
        #pragma unroll
        for (int kt = 0; kt < 4; ++kt)
            hf[kt] = *(const short8*)(hT + (nt * 16 + l15) * 136 + kt * 32 + quad * 8);
        floatx4 acc[6];
        #pragma unroll
        for (int j = 0; j < 6; ++j) acc[j] = (floatx4)0.f;
        #pragma unroll
        for (int kt = 0; kt < 4; ++kt)
            #pragma unroll
            for (int j = 0; j < 6; ++j) {
                // q/k transposed (rows=o, cols=pos); v natural (rows=pos, cols=ov)
                if (w * 6 + j < 16) acc[j] = mfma16(wf[j][kt], hf[kt], acc[j]);
                else                acc[j] = mfma16(hf[kt], wf[j][kt], acc[j]);
            }
        // scatter: one uint2 (b64) write per tile
        #pragma unroll
        for (int j = 0; j < 6; ++j) {
            int T = w * 6 + j;
            if (T < 8) {            // q: C[o][pos] -> qbuf[n=pos][c=o]
                u32 a01 = pkbf((acc[j][0] + bq4[j].x) * QSCALE,
                               (acc[j][1] + bq4[j].y) * QSCALE);
                u32 a23 = pkbf((acc[j][2] + bq4[j].z) * QSCALE,
                               (acc[j][3] + bq4[j].w) * QSCALE);
                *(uint2*)(qbuf + (nt * 16 + l15) * 132 + T * 16 + quad * 4) =
                    make_uint2(a01, a23);
            } else if (T < 16) {    // k -> kbuf[n][c]
                u32 a01 = pkbf(acc[j][0] + bq4[j].x, acc[j][1] + bq4[j].y);
                u32 a23 = pkbf(acc[j][2] + bq4[j].z, acc[j][3] + bq4[j].w);
                *(uint2*)(kbuf + (nt * 16 + l15) * 132 + (T - 8) * 16 + quad * 4) =
                    make_uint2(a01, a23);
            } else {                // v: C[pos][ov] -> vbuf[c=ov][n=pos]
                u32 a01 = pkbf(acc[j][0] + bv[j], acc[j][1] + bv[j]);
                u32 a23 = pkbf(acc[j][2] + bv[j], acc[j][3] + bv[j]);
                *(uint2*)(vbuf + ((T - 16) * 16 + l15) * 36 + nt * 16 + quad * 4) =
                    make_uint2(a01, a23);
            }
        }
    }
    __syncthreads();

    // cooperative coalesced stores
    {   // q,k: [32n][128c] -> contiguous 4096-elem global region each
        u16* qg = qT + ((size_t)b * SEQ + n0) * CH;
        u16* kg = kT + ((size_t)b * SEQ + n0) * CH;
        #pragma unroll
        for (int rep = 0; rep < 2; ++rep) {
            int idx = rep * 256 + t;
            int n = idx >> 4, c8 = (idx & 15) * 8;
            *(uint4*)(qg + n * CH + c8) = *(const uint4*)(qbuf + n * 132 + c8);
            *(uint4*)(kg + n * CH + c8) = *(const uint4*)(kbuf + n * 132 + c8);
        }
        // v: [128c][32n] -> per-c rows of 64 B
        #pragma unroll
        for (int rep = 0; rep < 2; ++rep) {
            int idx = rep * 256 + t;
            int c = idx >> 2, n8 = (idx & 3) * 8;
            *(uint4*)(v + ((size_t)(b * CH + c)) * SEQ + n0 + n8) =
                *(const uint4*)(vbuf + c * 36 + n8);
        }
    }
}

// ---------------- Kernel 3: MFMA flash attention (fixed-max softmax) -----------
// r26: 512 blocks = (b, iblk of 128 i, js of 4), 2 blk/CU. 32 chunks of BN=32;
// 4-buffer LDS ring; one barrier per TWO chunks. NEW: the two chunks in each
// region are SOFTWARE-PIPELINED: QK(A);QK(B) issued as one MFMA cluster, then
// SM(A) -> PV(A) -> SM(B) -> PV(B). QK(B)'s issue stream covers QK(A)->SM(A)
// MFMA latency; SM(B)'s VALU overlaps PV(A)'s in-flight MFMAs. Same per-(i,j)
// math and same o/lacc accumulation order as r19-r25 -> bit-identical.
// K XOR-swizzled; V slot involution; -SMAX in MFMA C-init; l via ones-MFMA.
__global__ __launch_bounds__(256, 2) void flash_attn(
        const u16* __restrict__ qT, const u16* __restrict__ kT,
        const u16* __restrict__ v, u16* __restrict__ partO,
        float* __restrict__ lbuf) {
    __shared__ __align__(16) u16 smem[32768];   // 65536 B (4 x K+V buffers)

    int bx = blockIdx.x;                   // 512, js fastest
    int js = bx & 3, iblk = (bx >> 2) & 31, b = bx >> 7;
    int t = threadIdx.x, w = t >> 6, lane = t & 63;
    int quad = lane >> 4, l15 = lane & 15;
    int i0 = iblk * 128, j0 = js * 1024;

    const u16* kTb = kT + ((size_t)b * SEQ + j0) * CH;
    const u16* vb  = v  + (size_t)b * CH * SEQ + j0;

    // K swizzle constants (u16 units)
    int xm  = (l15 & 7) << 3;              // K read-side XOR (row&7 == l15&7)
    int km  = ((w * 4 + quad) & 7) << 3;   // K-source XOR (dest row&7)
    int kso = (l15 * 8) ^ km;              // K src col offset within 128-u16 row
    int cswz[4];
    #pragma unroll
    for (int kt = 0; kt < 4; ++kt) cswz[kt] = (kt * 32 + quad * 8) ^ xm;

    // V slot involution (r18-verified): write-side lane permute; read-side XOR
    int lx  = lane ^ (lane >> 3);          // bijection on 0..63
    int vxm = ((l15 >> 1) & 7) << 3;       // read XOR, constant per lane

    // ones fragment (bf16 1.0 x8) for the l-row MFMA
    union { u32 u[4]; short8 s; } ONES;
    ONES.u[0] = 0x3F803F80u; ONES.u[1] = 0x3F803F80u;
    ONES.u[2] = 0x3F803F80u; ONES.u[3] = 0x3F803F80u;
    const short8 ones8 = ONES.s;

    // DMA issue for chunk nx -> buf[nx&3].
    auto issue = [&](int nx) {
        int bb = (nx & 3) * 8192;          // u16: K(4096)+V(4096) buffer stride
        const u16* ks = kTb + (size_t)nx * 4096 + (w * 4 + quad) * 128 + kso;
        const u16* vs = vb + (size_t)(w * 16 + (lx >> 2)) * SEQ + nx * 32
                        + (lx & 3) * 8;
        u16* kd = smem + bb + w * 512;
        u16* vd = smem + bb + 4096 + w * 512;
        #pragma unroll
        for (int r = 0; r < 2; ++r) {
            gl_lds16(ks + r * 2048, kd + r * 2048);
            gl_lds16(vs + (size_t)r * 64 * SEQ, vd + r * 2048);
        }
    };

    issue(0); issue(1);                    // chunks 0,1 -> bufs 0,1, in flight

    // ---- Q fragments straight from global (one-time, 64B segments) ----
    short8 qf[2][4];
    {
        const u16* qb = qT + ((size_t)b * SEQ + i0) * CH;
        #pragma unroll
        for (int it = 0; it < 2; ++it)
            #pragma unroll
            for (int kt = 0; kt < 4; ++kt)
                qf[it][kt] = *(const short8*)(qb +
                    (size_t)(w * 32 + it * 16 + l15) * CH + kt * 32 + quad * 8);
    }
    __syncthreads();                       // chunk-0/1 DMA (and qf) complete

    floatx4 o[8][2];
    #pragma unroll
    for (int mt = 0; mt < 8; ++mt) { o[mt][0] = (floatx4)0.f; o[mt][1] = (floatx4)0.f; }
    floatx4 lacc[2];
    lacc[0] = (floatx4)0.f; lacc[1] = (floatx4)0.f;

    for (int k2 = 0; k2 < 16; ++k2) {
        int c0 = k2 * 2;
        if (k2 < 15) { issue(c0 + 2); issue(c0 + 3); }

        const u16* ktsA = smem + (c0 & 3) * 8192;
        const u16* vtsA = ktsA + 4096;
        const u16* ktsB = smem + ((c0 + 1) & 3) * 8192;
        const u16* vtsB = ktsB + 4096;

        // ---- QK(A) + QK(B): one 32-MFMA cluster ----
        floatx4 sA[2][2], sB[2][2];
        #pragma unroll
        for (int jt = 0; jt < 2; ++jt) {
            sA[jt][0] = (floatx4)(-SMAX); sA[jt][1] = (floatx4)(-SMAX);
            sB[jt][0] = (floatx4)(-SMAX); sB[jt][1] = (floatx4)(-SMAX);
        }
        __builtin_amdgcn_s_setprio(1);
        #pragma unroll
        for (int jt = 0; jt < 2; ++jt)
            #pragma unroll
            for (int kt = 0; kt < 4; ++kt) {
                short8 kfA = *(const short8*)(ktsA + (jt * 16 + l15) * 128 + cswz[kt]);
                sA[jt][0] = mfma16(kfA, qf[0][kt], sA[jt][0]);
                sA[jt][1] = mfma16(kfA, qf[1][kt], sA[jt][1]);
            }
        #pragma unroll
        for (int jt = 0; jt < 2; ++jt)
            #pragma unroll
            for (int kt = 0; kt < 4; ++kt) {
                short8 kfB = *(const short8*)(ktsB + (jt * 16 + l15) * 128 + cswz[kt]);
                sB[jt][0] = mfma16(kfB, qf[0][kt], sB[jt][0]);
                sB[jt][1] = mfma16(kfB, qf[1][kt], sB[jt][1]);
            }
        __builtin_amdgcn_s_setprio(0);

        // ---- SM(A): sA ready (QK(B) issue covered the latency) ----
        u32 PA[2][2][2];   // [it][jt][h]
        #pragma unroll
        for (int it = 0; it < 2; ++it)
            #pragma unroll
            for (int jt = 0; jt < 2; ++jt) {
                PA[it][jt][0] = pkbf(exp2f(sA[jt][it][0]), exp2f(sA[jt][it][1]));
                PA[it][jt][1] = pkbf(exp2f(sA[jt][it][2]), exp2f(sA[jt][it][3]));
            }

        // ---- PV(A) ----
        __builtin_amdgcn_s_setprio(1);
        {
            short8 pf0 = pfrag(PA[0][0][0], PA[0][1][0], PA[0][0][1], PA[0][1][1]);
            short8 pf1 = pfrag(PA[1][0][0], PA[1][1][0], PA[1][0][1], PA[1][1][1]);
            lacc[0] = mfma16(ones8, pf0, lacc[0]);
            lacc[1] = mfma16(ones8, pf1, lacc[1]);
            #pragma unroll
            for (int mt = 0; mt < 8; ++mt) {
                short8 vf = *(const short8*)(vtsA +
                    ((((mt * 16 + l15) * 32) + quad * 8) ^ vxm));
                o[mt][0] = mfma16(vf, pf0, o[mt][0]);
                o[mt][1] = mfma16(vf, pf1, o[mt][1]);
            }
        }
        __builtin_amdgcn_s_setprio(0);

        // ---- SM(B): VALU overlaps PV(A)'s in-flight MFMAs ----
        u32 PB[2][2][2];
        #pragma unroll
        for (int it = 0; it < 2; ++it)
            #pragma unroll
            for (int jt = 0; jt < 2; ++jt) {
                PB[it][jt][0] = pkbf(exp2f(sB[jt][it][0]), exp2f(sB[jt][it][1]));
                PB[it][jt][1] = pkbf(exp2f(sB[jt][it][2]), exp2f(sB[jt][it][3]));
            }

        // ---- PV(B) ----
        __builtin_amdgcn_s_setprio(1);
        {
            short8 pf0 = pfrag(PB[0][0][0], PB[0][1][0], PB[0][0][1], PB[0][1][1]);
            short8 pf1 = pfrag(PB[1][0][0], PB[1][1][0], PB[1][0][1], PB[1][1][1]);
            lacc[0] = mfma16(ones8, pf0, lacc[0]);
            lacc[1] = mfma16(ones8, pf1, lacc[1]);
            #pragma unroll
            for (int mt = 0; mt < 8; ++mt) {
                short8 vf = *(const short8*)(vtsB +
                    ((((mt * 16 + l15) * 32) + quad * 8) ^ vxm));
                o[mt][0] = mfma16(vf, pf0, o[mt][0]);
                o[mt][1] = mfma16(vf, pf1, o[mt][1]);
            }
        }
        __builtin_amdgcn_s_setprio(0);

        if (k2 < 15) __syncthreads();      // fences ring bufs + drains DMA
    }

    // ---- epilogue: partial O (bf16) in [i][c] layout, packed stores ----
    // C layout: i = w*32 + it*16 + l15 (col), c = mt*16 + quad*4 + r (row).
    int bi = b * 32 + iblk;
    u16* pb = partO + ((size_t)(js * 128 + bi)) * 16384;   // [128 i][128 c]
    #pragma unroll
    for (int it = 0; it < 2; ++it) {
        int i = w * 32 + it * 16 + l15;
        #pragma unroll
        for (int mt = 0; mt < 8; ++mt) {
            uint2 pk = make_uint2(pkbf(o[mt][it][0], o[mt][it][1]),
                                  pkbf(o[mt][it][2], o[mt][it][3]));
            *(uint2*)(pb + i * 128 + mt * 16 + quad * 4) = pk;
        }
    }
    // l: every row of the ones-MFMA result holds l[col=l15].
    float* lb = lbuf + ((size_t)(js * 128 + bi)) * 128;
    if (lane < 16) {
        lb[w * 32 + l15]      = lacc[0][0];
        lb[w * 32 + 16 + l15] = lacc[1][0];
    }
}

// ---------------- Kernel 4: merge 4 partials + MFMA out-proj + residual --------
// 512 blocks = (b, iblk, quarter of 32 pos). Fixed softmax shift -> merge is
// just (sum of partials) * 1/(sum of l). partO [i][c]: coalesced row reads.
__global__ __launch_bounds__(256, 2) void merge_out(
        const u16* __restrict__ partO, const float* __restrict__ lbuf,
        const u16* __restrict__ wo, const float* __restrict__ b_out,
        const float* __restrict__ x, float* __restrict__ out) {
    __shared__ __align__(16) u16 h2T[32 * 136];
    __shared__ float fac[32];
    int bx = blockIdx.x;           // 512
    int qtr = bx & 3, iblk = (bx >> 2) & 31, b = bx >> 7;
    int bi = b * 32 + iblk;
    int i_base = qtr * 32;
    int t = threadIdx.x, w = t >> 6, lane = t & 63;
    int quad = lane >> 4, l15 = lane & 15;

    short8 wf[2][4];
    #pragma unroll
    for (int j = 0; j < 2; ++j)
        #pragma unroll
        for (int kt = 0; kt < 4; ++kt)
            wf[j][kt] = *(const short8*)(wo + ((w * 2 + j) * 16 + l15) * 128 + kt * 32 + quad * 8);

    if (t < 32) {
        int i = i_base + t;
        float lv = 0.f;
        #pragma unroll
        for (int s = 0; s < 4; ++s)
            lv += lbuf[((size_t)(s * 128 + bi)) * 128 + i];
        fac[t] = 1.f / lv;
    }
    __syncthreads();

    // merge: thread -> (il = t>>3 in 0..31, oct = t&7 -> 16-c strip)
    {
        int il = t >> 3, oct = t & 7;
        int i = i_base + il;
        float accv[16];
        #pragma unroll
        for (int e = 0; e < 16; ++e) accv[e] = 0.f;
        for (int s = 0; s < 4; ++s) {
            const u16* pb = partO + ((size_t)(s * 128 + bi)) * 16384
                            + i * 128 + oct * 16;
            u16 a[16];
            *(uint4*)(a)     = *(const uint4*)(pb);
            *(uint4*)(a + 8) = *(const uint4*)(pb + 8);
            #pragma unroll
            for (int e = 0; e < 16; ++e) accv[e] += bf2f(a[e]);
        }
        float fs = fac[il];
        #pragma unroll
        for (int e = 0; e < 16; ++e) accv[e] *= fs;
        uint4 lo = make_uint4(pkbf(accv[0],  accv[1]),  pkbf(accv[2],  accv[3]),
                              pkbf(accv[4],  accv[5]),  pkbf(accv[6],  accv[7]));
        uint4 hi = make_uint4(pkbf(accv[8],  accv[9]),  pkbf(accv[10], accv[11]),
                              pkbf(accv[12], accv[13]), pkbf(accv[14], accv[15]));
        *(uint4*)(h2T + il * 136 + oct * 16)     = lo;
        *(uint4*)(h2T + il * 136 + oct * 16 + 8) = hi;
    }
    __syncthreads();

    floatx4 acc[2][2];
    #pragma unroll
    for (int j = 0; j < 2; ++j) { acc[j][0] = (floatx4)0.f; acc[j][1] = (floatx4)0.f; }
    #pragma unroll
    for (int nt = 0; nt < 2; ++nt)
        #pragma unroll
        for (int kt = 0; kt < 4; ++kt) {
            short8 hf = *(const short8*)(h2T + (nt * 16 + l15) * 136 + kt * 32 + quad * 8);
            acc[0][nt] = mfma16(wf[0][kt], hf, acc[0][nt]);
            acc[1][nt] = mfma16(wf[1][kt], hf, acc[1][nt]);
        }

    int n_base = iblk * 128 + i_base;
    #pragma unroll
    for (int j = 0; j < 2; ++j)
        #pragma unroll
        for (int r = 0; r < 4; ++r) {
            int o = w * 32 + j * 16 + quad * 4 + r;
            float bo = b_out[o];
            #pragma unroll
            for (int nt = 0; nt < 2; ++nt) {
                int n = n_base + nt * 16 + l15;
                size_t idx = ((size_t)(b * 128 + o)) * SEQ + n;
                out[idx] = acc[j][nt][r] + bo + x[idx];
            }
        }
}

// ---------------- launch -------------------------------------------------------
extern "C" void kernel_launch(void* const* d_in, const int* in_sizes, int n_in,
                              void* d_out, int out_size, void* d_ws, size_t ws_size,
                              hipStream_t stream) {
    const float* x     = (const float*)d_in[0];
    const float* gn_w  = (const float*)d_in[1];
    const float* gn_b  = (const float*)d_in[2];
    const float* w_qkv = (const float*)d_in[3];
    const float* b_qkv = (const float*)d_in[4];
    const float* w_out = (const float*)d_in[5];
    const float* b_out = (const float*)d_in[6];
    float* out = (float*)d_out;

    char* ws = (char*)d_ws;
    float* part = (float*)ws;                  //   2 KB @ 0
    u16*  wq  = (u16*)(ws + 4096);             //  96 KB
    u16*  wo  = (u16*)(ws + 102400);           //  32 KB
    u16*  qT  = (u16*)(ws + 135168);           //   4 MB [b][n][c]
    u16*  kT  = (u16*)(ws + 4329472);          //   4 MB [b][n][c]
    u16*  v   = (u16*)(ws + 8523776);          //   4 MB [b][c][n]
    u16*  pO  = (u16*)(ws + 12718080);         //  16 MB partials [js][bi][i][c]
    float* lb = (float*)(ws + 29495296);       // 256 KB
    // total ~29.8 MB

    gn_wconv<<<320, 256, 0, stream>>>(x, part, w_qkv, w_out, wq, wo);
    qkv_fused<<<512, 256, 0, stream>>>(x, gn_w, gn_b, part, wq, b_qkv, qT, kT, v);
    flash_attn<<<512, 256, 0, stream>>>(qT, kT, v, pO, lb);
    merge_out<<<512, 256, 0, stream>>>(pO, lb, wo, b_out, x, out);
}

// Round 17
// 137.840 us; speedup vs baseline: 1.0148x; 1.0148x over previous
//
#include <hip/hip_runtime.h>
#include <hip/hip_bf16.h>

// AttentionBlock B=4, C=128, N=4096.   (FINAL = r21/r25 config — measured best
// 138.55 µs, reproduced 139.48. Session ledger, all counter-verified:
//  - flash invariant ~53µs across 6 structures (occupancy, conflicts, barrier
//    density, SW pipelining, reg pipelines, DMA depth) — mixed-bound
//    LDS~50%/VALU~44%/MFMA~27%, next step would be a CK-style rewrite.
//  - ticket-fusion of merge (-97µs: de-parallelized + L2 thrash), cooperative
//    launch (dropped under graph capture), nt stores (WRITE 16.6->40.4 MB
//    amplification: 8B/lane stores bypass L2 write-combining) — reverted.
//  - ~60µs of e2e is fixed harness/boundary overhead, invariant to aux edits.)
// gn_wconv (320 blocks — 256 stats + 64 vectorized weight-convert)
// -> qkv_fused (GN finalize+apply + MFMA QKV, transposed tile outputs ->
//               b64 LDS scatter; coalesced stores)
// -> flash_attn (4-buffer DMA ring, 1 barrier/2 chunks, K XOR swizzle,
//                V slot involution, in-reg P via permlane, -SMAX in MFMA
//                C-init, l via ones-MFMA)
// -> merge_out (sum 4 partials * 1/l + MFMA out-proj + bias + residual)

#define CH 128
#define SEQ 4096
#define EPSV 1e-5f
// 1/sqrt(128) * log2(e): softmax runs in base-2 domain
#define QSCALE (0.08838834764831845f * 1.4426950408889634f)
// fixed softmax shift: base-2 logits bounded |s2| <~ 15; exp2 overflows only
// at s2-M > 127 -> huge margin. Same M for all j-splits makes merge factors
// collapse to 1/sum(l). Folded into the MFMA accumulator init.
#define SMAX 24.0f

typedef unsigned short u16;
typedef unsigned int u32;
typedef __attribute__((ext_vector_type(8))) short short8;   // 8 bf16 (4 VGPRs)
typedef __attribute__((ext_vector_type(4))) float floatx4;  // MFMA C/D
typedef __attribute__((ext_vector_type(2))) unsigned int u32x2;

__device__ __forceinline__ float bf2f(u16 h) {
    return __uint_as_float(((u32)h) << 16);
}
__device__ __forceinline__ u16 f2bf(float f) {
    u32 u = __float_as_uint(f);
    return (u16)((u + 0x7fffu + ((u >> 16) & 1u)) >> 16);
}
__device__ __forceinline__ u32 pkbf(float a, float b) {   // packed RNE cvt (low=a)
    __hip_bfloat162 h = __float22bfloat162_rn(make_float2(a, b));
    return *(u32*)&h;
}
__device__ __forceinline__ floatx4 mfma16(short8 a, short8 b, floatx4 c) {
    return __builtin_amdgcn_mfma_f32_16x16x32_bf16(a, b, c, 0, 0, 0);
}
// async global->LDS DMA, 16 B/lane. LDS dest must be wave-uniform (HW adds
// lane*16); global source is per-lane (carries the inverse swizzle).
__device__ __forceinline__ void gl_lds16(const u16* g, u16* l) {
    __builtin_amdgcn_global_load_lds(
        (const __attribute__((address_space(1))) unsigned int*)g,
        (__attribute__((address_space(3))) unsigned int*)l,
        16, 0, 0);
}

// Build PV B-fragment (16x16x32) from in-register P, no LDS.
// Source lane (l15, sq) holds P(i, j=jt*16+4*sq+r); P32[jt][h] packs r=2h,2h+1.
// Target lane (l15,q) needs j = 8q + e. Verified r11-r26 (absmax-identical).
__device__ __forceinline__ short8 pfrag(u32 a0, u32 b0, u32 a1, u32 b1) {
    u32x2 s0 = __builtin_amdgcn_permlane32_swap(a0, b0, false, false);
    u32x2 t0 = __builtin_amdgcn_permlane16_swap(s0.x, s0.y, false, false);
    u32x2 s1 = __builtin_amdgcn_permlane32_swap(a1, b1, false, false);
    u32x2 t1 = __builtin_amdgcn_permlane16_swap(s1.x, s1.y, false, false);
    union { u32 u[4]; short8 s; } U;
    U.u[0] = t0.x; U.u[1] = t1.x; U.u[2] = t0.y; U.u[3] = t1.y;
    return U.s;
}

// ---------------- Kernel 1: GN partial stats + weight conversion ---------------
// 320 blocks: 0..255 stats (bg,sub); 256..319 weight convert, 4 elems/thread.
__global__ void gn_wconv(const float* __restrict__ x, float* __restrict__ part,
                         const float* __restrict__ w_qkv, const float* __restrict__ w_out,
                         u16* __restrict__ wq, u16* __restrict__ wo) {
    if (blockIdx.x >= 256) {
        int i = ((blockIdx.x - 256) * 256 + threadIdx.x) * 4;   // 65536 total
        if (i < 49152) {
            float4 v = *(const float4*)(w_qkv + i);
            *(uint2*)(wq + i) = make_uint2(pkbf(v.x, v.y), pkbf(v.z, v.w));
        } else {
            float4 v = *(const float4*)(w_out + (i - 49152));
            *(uint2*)(wo + (i - 49152)) = make_uint2(pkbf(v.x, v.y), pkbf(v.z, v.w));
        }
        return;
    }
    int bg = blockIdx.x >> 3, sub = blockIdx.x & 7;
    const float4* xp = (const float4*)(x + (size_t)bg * 65536 + sub * 8192);
    float s = 0.f, sq = 0.f;
    for (int r = 0; r < 8; ++r) {
        float4 v = xp[threadIdx.x + 256 * r];
        s  += v.x + v.y + v.z + v.w;
        sq += v.x*v.x + v.y*v.y + v.z*v.z + v.w*v.w;
    }
    for (int off = 32; off; off >>= 1) {
        s  += __shfl_down(s, off, 64);
        sq += __shfl_down(sq, off, 64);
    }
    __shared__ float ls[8];
    int wave = threadIdx.x >> 6, lane = threadIdx.x & 63;
    if (lane == 0) { ls[wave*2] = s; ls[wave*2+1] = sq; }
    __syncthreads();
    if (threadIdx.x == 0) {
        float ts = 0.f, tq = 0.f;
        for (int w = 0; w < 4; ++w) { ts += ls[w*2]; tq += ls[w*2+1]; }
        part[blockIdx.x * 2]     = ts;
        part[blockIdx.x * 2 + 1] = tq;
    }
}

// ---------------- Kernel 2: fused GN-apply + MFMA QKV projection ---------------
// 512 blocks = (b, 32-pos chunk). hT[32n][136c] in LDS; wave owns 6 o-tiles.
// Tiles computed TRANSPOSED (operand swap = exact transpose) so each thread's
// 4 C-values are contiguous in the stage buffer -> one ds_write_b64 per tile.
__global__ __launch_bounds__(256, 2) void qkv_fused(
        const float* __restrict__ x, const float* __restrict__ gw,
        const float* __restrict__ gb, const float* __restrict__ part,
        const u16* __restrict__ wq, const float* __restrict__ b_qkv,
        u16* __restrict__ qT, u16* __restrict__ kT, u16* __restrict__ v) {
    __shared__ __align__(16) u16 hT[32 * 136];     // input stage
    __shared__ __align__(16) u16 qbuf[32 * 132];   // [n][c] padded
    __shared__ __align__(16) u16 kbuf[32 * 132];
    __shared__ __align__(16) u16 vbuf[128 * 36];   // [c][n] padded
    __shared__ float cw[128], cb[128];
    int bx = blockIdx.x;            // 512
    int nc = bx & 127, b = bx >> 7;
    int n0 = nc * 32;
    int t = threadIdx.x, w = t >> 6, lane = t & 63;
    int quad = lane >> 4, l15 = lane & 15;

    // finalize GN stats -> per-channel scale/bias
    if (t < 128) {
        int g = t >> 4;
        float s = 0.f, sq = 0.f;
        #pragma unroll
        for (int u = 0; u < 8; ++u) {
            s  += part[((b * 8 + g) * 8 + u) * 2];
            sq += part[((b * 8 + g) * 8 + u) * 2 + 1];
        }
        float mean = s / 65536.f;
        float rstd = rsqrtf(sq / 65536.f - mean * mean + EPSV);
        float wgt = gw[t] * rstd;
        cw[t] = wgt;
        cb[t] = gb[t] - mean * wgt;
    }

    // weight fragments: wave w -> o-tiles w*6 .. w*6+5
    short8 wf[6][4];
    float4 bq4[6];      // q/k tiles: bias for o = T*16 + quad*4 + r
    float  bv[6];       // v tiles: bias for ov = (T-16)*16 + l15
    #pragma unroll
    for (int j = 0; j < 6; ++j) {
        int T = w * 6 + j;
        #pragma unroll
        for (int kt = 0; kt < 4; ++kt)
            wf[j][kt] = *(const short8*)(wq + (T * 16 + l15) * 128 + kt * 32 + quad * 8);
        if (T < 16) bq4[j] = *(const float4*)(b_qkv + T * 16 + quad * 4);
        else        bv[j]  = b_qkv[256 + (T - 16) * 16 + l15];
    }
    __syncthreads();

    // stage GN'd x transposed (32 pos x 128 c); packed converts
    #pragma unroll
    for (int r = 0; r < 4; ++r) {
        int u = r * 256 + t;
        int c = u >> 3, col = (u & 7) * 4;
        float wgt = cw[c], bs = cb[c];
        float4 xv = *(const float4*)(x + ((size_t)(b * 128 + c)) * SEQ + n0 + col);
        u32 p01 = pkbf(fmaf(xv.x, wgt, bs), fmaf(xv.y, wgt, bs));
        u32 p23 = pkbf(fmaf(xv.z, wgt, bs), fmaf(xv.w, wgt, bs));
        hT[(col + 0) * 136 + c] = (u16)p01;
        hT[(col + 1) * 136 + c] = (u16)(p01 >> 16);
        hT[(col + 2) * 136 + c] = (u16)p23;
        hT[(col + 3) * 136 + c] = (u16)(p23 >> 16);
    }
    __syncthreads();

    #pragma unroll
    for (int nt = 0; nt < 2; ++nt) {
        short8 hf[4];
        #pragma unroll
        for (int kt = 0; kt < 4; ++kt)
            hf[kt] = *(const short8*)(hT + (nt * 16 + l15) * 136 + kt * 32 + quad * 8);
        floatx4 acc[6];
        #pragma unroll
        for (int j = 0; j < 6; ++j) acc[j] = (floatx4)0.f;
        #pragma unroll
        for (int kt = 0; kt < 4; ++kt)
            #pragma unroll
            for (int j = 0; j < 6; ++j) {
                // q/k transposed (rows=o, cols=pos); v natural (rows=pos, cols=ov)
                if (w * 6 + j < 16) acc[j] = mfma16(wf[j][kt], hf[kt], acc[j]);
                else                acc[j] = mfma16(hf[kt], wf[j][kt], acc[j]);
            }
        // scatter: one uint2 (b64) write per tile
        #pragma unroll
        for (int j = 0; j < 6; ++j) {
            int T = w * 6 + j;
            if (T < 8) {            // q: C[o][pos] -> qbuf[n=pos][c=o]
                u32 a01 = pkbf((acc[j][0] + bq4[j].x) * QSCALE,
                               (acc[j][1] + bq4[j].y) * QSCALE);
                u32 a23 = pkbf((acc[j][2] + bq4[j].z) * QSCALE,
                               (acc[j][3] + bq4[j].w) * QSCALE);
                *(uint2*)(qbuf + (nt * 16 + l15) * 132 + T * 16 + quad * 4) =
                    make_uint2(a01, a23);
            } else if (T < 16) {    // k -> kbuf[n][c]
                u32 a01 = pkbf(acc[j][0] + bq4[j].x, acc[j][1] + bq4[j].y);
                u32 a23 = pkbf(acc[j][2] + bq4[j].z, acc[j][3] + bq4[j].w);
                *(uint2*)(kbuf + (nt * 16 + l15) * 132 + (T - 8) * 16 + quad * 4) =
                    make_uint2(a01, a23);
            } else {                // v: C[pos][ov] -> vbuf[c=ov][n=pos]
                u32 a01 = pkbf(acc[j][0] + bv[j], acc[j][1] + bv[j]);
                u32 a23 = pkbf(acc[j][2] + bv[j], acc[j][3] + bv[j]);
                *(uint2*)(vbuf + ((T - 16) * 16 + l15) * 36 + nt * 16 + quad * 4) =
                    make_uint2(a01, a23);
            }
        }
    }
    __syncthreads();

    // cooperative coalesced stores
    {   // q,k: [32n][128c] -> contiguous 4096-elem global region each
        u16* qg = qT + ((size_t)b * SEQ + n0) * CH;
        u16* kg = kT + ((size_t)b * SEQ + n0) * CH;
        #pragma unroll
        for (int rep = 0; rep < 2; ++rep) {
            int idx = rep * 256 + t;
            int n = idx >> 4, c8 = (idx & 15) * 8;
            *(uint4*)(qg + n * CH + c8) = *(const uint4*)(qbuf + n * 132 + c8);
            *(uint4*)(kg + n * CH + c8) = *(const uint4*)(kbuf + n * 132 + c8);
        }
        // v: [128c][32n] -> per-c rows of 64 B
        #pragma unroll
        for (int rep = 0; rep < 2; ++rep) {
            int idx = rep * 256 + t;
            int c = idx >> 2, n8 = (idx & 3) * 8;
            *(uint4*)(v + ((size_t)(b * CH + c)) * SEQ + n0 + n8) =
                *(const uint4*)(vbuf + c * 36 + n8);
        }
    }
}

// ---------------- Kernel 3: MFMA flash attention (fixed-max softmax) -----------
// 512 blocks = (b, iblk of 128 i, js of 4), 2 blk/CU. 32 chunks of BN=32;
// 4-buffer LDS ring; one barrier per TWO chunks (the two chunks in each
// region are independent -> cross-chunk ILP). K XOR-swizzled (linear DMA
// dest, inverse-swizzled source, swizzled reads). V slot involution
// phys = L ^ ((L>>3)&7): source re-addressed with lx = lane^(lane>>3),
// reads XOR vxm. -SMAX in MFMA C-init; l via ones-MFMA; P in registers.
__global__ __launch_bounds__(256, 2) void flash_attn(
        const u16* __restrict__ qT, const u16* __restrict__ kT,
        const u16* __restrict__ v, u16* __restrict__ partO,
        float* __restrict__ lbuf) {
    __shared__ __align__(16) u16 smem[32768];   // 65536 B (4 x K+V buffers)

    int bx = blockIdx.x;                   // 512, js fastest
    int js = bx & 3, iblk = (bx >> 2) & 31, b = bx >> 7;
    int t = threadIdx.x, w = t >> 6, lane = t & 63;
    int quad = lane >> 4, l15 = lane & 15;
    int i0 = iblk * 128, j0 = js * 1024;

    const u16* kTb = kT + ((size_t)b * SEQ + j0) * CH;
    const u16* vb  = v  + (size_t)b * CH * SEQ + j0;

    // K swizzle constants (u16 units)
    int xm  = (l15 & 7) << 3;              // K read-side XOR (row&7 == l15&7)
    int km  = ((w * 4 + quad) & 7) << 3;   // K-source XOR (dest row&7)
    int kso = (l15 * 8) ^ km;              // K src col offset within 128-u16 row
    int cswz[4];
    #pragma unroll
    for (int kt = 0; kt < 4; ++kt) cswz[kt] = (kt * 32 + quad * 8) ^ xm;

    // V slot involution (r18-verified): write-side lane permute; read-side XOR
    int lx  = lane ^ (lane >> 3);          // bijection on 0..63
    int vxm = ((l15 >> 1) & 7) << 3;       // read XOR, constant per lane

    // ones fragment (bf16 1.0 x8) for the l-row MFMA
    union { u32 u[4]; short8 s; } ONES;
    ONES.u[0] = 0x3F803F80u; ONES.u[1] = 0x3F803F80u;
    ONES.u[2] = 0x3F803F80u; ONES.u[3] = 0x3F803F80u;
    const short8 ones8 = ONES.s;

    // DMA issue for chunk nx -> buf[nx&3].
    auto issue = [&](int nx) {
        int bb = (nx & 3) * 8192;          // u16: K(4096)+V(4096) buffer stride
        const u16* ks = kTb + (size_t)nx * 4096 + (w * 4 + quad) * 128 + kso;
        const u16* vs = vb + (size_t)(w * 16 + (lx >> 2)) * SEQ + nx * 32
                        + (lx & 3) * 8;
        u16* kd = smem + bb + w * 512;
        u16* vd = smem + bb + 4096 + w * 512;
        #pragma unroll
        for (int r = 0; r < 2; ++r) {
            gl_lds16(ks + r * 2048, kd + r * 2048);
            gl_lds16(vs + (size_t)r * 64 * SEQ, vd + r * 2048);
        }
    };

    issue(0); issue(1);                    // chunks 0,1 -> bufs 0,1, in flight

    // ---- Q fragments straight from global (one-time, 64B segments) ----
    short8 qf[2][4];
    {
        const u16* qb = qT + ((size_t)b * SEQ + i0) * CH;
        #pragma unroll
        for (int it = 0; it < 2; ++it)
            #pragma unroll
            for (int kt = 0; kt < 4; ++kt)
                qf[it][kt] = *(const short8*)(qb +
                    (size_t)(w * 32 + it * 16 + l15) * CH + kt * 32 + quad * 8);
    }
    __syncthreads();                       // chunk-0/1 DMA (and qf) complete

    floatx4 o[8][2];
    #pragma unroll
    for (int mt = 0; mt < 8; ++mt) { o[mt][0] = (floatx4)0.f; o[mt][1] = (floatx4)0.f; }
    floatx4 lacc[2];
    lacc[0] = (floatx4)0.f; lacc[1] = (floatx4)0.f;

    for (int k2 = 0; k2 < 16; ++k2) {
        int c0 = k2 * 2;
        if (k2 < 15) { issue(c0 + 2); issue(c0 + 3); }

        #pragma unroll
        for (int cc = 0; cc < 2; ++cc) {
            int ch = c0 + cc;
            const u16* kts = smem + (ch & 3) * 8192;
            const u16* vts = kts + 4096;

            // ---- scores S^T: s[jt][it], row=j(quad*4+r), col=i(l15) ----
            floatx4 s[2][2];
            #pragma unroll
            for (int jt = 0; jt < 2; ++jt) {
                s[jt][0] = (floatx4)(-SMAX); s[jt][1] = (floatx4)(-SMAX);
            }
            __builtin_amdgcn_s_setprio(1);
            #pragma unroll
            for (int jt = 0; jt < 2; ++jt)
                #pragma unroll
                for (int kt = 0; kt < 4; ++kt) {
                    short8 kf = *(const short8*)(kts + (jt * 16 + l15) * 128 + cswz[kt]);
                    s[jt][0] = mfma16(kf, qf[0][kt], s[jt][0]);
                    s[jt][1] = mfma16(kf, qf[1][kt], s[jt][1]);
                }
            __builtin_amdgcn_s_setprio(0);

            // ---- softmax numerator (base-2, pre-shifted) -> P in regs ----
            u32 P32[2][2][2];   // [it][jt][h]
            #pragma unroll
            for (int it = 0; it < 2; ++it)
                #pragma unroll
                for (int jt = 0; jt < 2; ++jt) {
                    P32[it][jt][0] = pkbf(exp2f(s[jt][it][0]), exp2f(s[jt][it][1]));
                    P32[it][jt][1] = pkbf(exp2f(s[jt][it][2]), exp2f(s[jt][it][3]));
                }

            // ---- PV: O^T[c][i] += V[c][j] * P[i][j]^T; l via ones MFMA ----
            __builtin_amdgcn_s_setprio(1);
            {
                short8 pf0 = pfrag(P32[0][0][0], P32[0][1][0],
                                   P32[0][0][1], P32[0][1][1]);
                short8 pf1 = pfrag(P32[1][0][0], P32[1][1][0],
                                   P32[1][0][1], P32[1][1][1]);
                lacc[0] = mfma16(ones8, pf0, lacc[0]);
                lacc[1] = mfma16(ones8, pf1, lacc[1]);
                #pragma unroll
                for (int mt = 0; mt < 8; ++mt) {
                    short8 vf = *(const short8*)(vts +
                        ((((mt * 16 + l15) * 32) + quad * 8) ^ vxm));
                    o[mt][0] = mfma16(vf, pf0, o[mt][0]);
                    o[mt][1] = mfma16(vf, pf1, o[mt][1]);
                }
            }
            __builtin_amdgcn_s_setprio(0);
        }

        if (k2 < 15) __syncthreads();      // fences ring bufs + drains DMA
    }

    // ---- epilogue: partial O (bf16) in [i][c] layout, packed stores ----
    // C layout: i = w*32 + it*16 + l15 (col), c = mt*16 + quad*4 + r (row).
    int bi = b * 32 + iblk;
    u16* pb = partO + ((size_t)(js * 128 + bi)) * 16384;   // [128 i][128 c]
    #pragma unroll
    for (int it = 0; it < 2; ++it) {
        int i = w * 32 + it * 16 + l15;
        #pragma unroll
        for (int mt = 0; mt < 8; ++mt) {
            uint2 pk = make_uint2(pkbf(o[mt][it][0], o[mt][it][1]),
                                  pkbf(o[mt][it][2], o[mt][it][3]));
            *(uint2*)(pb + i * 128 + mt * 16 + quad * 4) = pk;
        }
    }
    // l: every row of the ones-MFMA result holds l[col=l15].
    float* lb = lbuf + ((size_t)(js * 128 + bi)) * 128;
    if (lane < 16) {
        lb[w * 32 + l15]      = lacc[0][0];
        lb[w * 32 + 16 + l15] = lacc[1][0];
    }
}

// ---------------- Kernel 4: merge 4 partials + MFMA out-proj + residual --------
// 512 blocks = (b, iblk, quarter of 32 pos). Fixed softmax shift -> merge is
// just (sum of partials) * 1/(sum of l). partO [i][c]: coalesced row reads.
__global__ __launch_bounds__(256, 2) void merge_out(
        const u16* __restrict__ partO, const float* __restrict__ lbuf,
        const u16* __restrict__ wo, const float* __restrict__ b_out,
        const float* __restrict__ x, float* __restrict__ out) {
    __shared__ __align__(16) u16 h2T[32 * 136];
    __shared__ float fac[32];
    int bx = blockIdx.x;           // 512
    int qtr = bx & 3, iblk = (bx >> 2) & 31, b = bx >> 7;
    int bi = b * 32 + iblk;
    int i_base = qtr * 32;
    int t = threadIdx.x, w = t >> 6, lane = t & 63;
    int quad = lane >> 4, l15 = lane & 15;

    short8 wf[2][4];
    #pragma unroll
    for (int j = 0; j < 2; ++j)
        #pragma unroll
        for (int kt = 0; kt < 4; ++kt)
            wf[j][kt] = *(const short8*)(wo + ((w * 2 + j) * 16 + l15) * 128 + kt * 32 + quad * 8);

    if (t < 32) {
        int i = i_base + t;
        float lv = 0.f;
        #pragma unroll
        for (int s = 0; s < 4; ++s)
            lv += lbuf[((size_t)(s * 128 + bi)) * 128 + i];
        fac[t] = 1.f / lv;
    }
    __syncthreads();

    // merge: thread -> (il = t>>3 in 0..31, oct = t&7 -> 16-c strip)
    {
        int il = t >> 3, oct = t & 7;
        int i = i_base + il;
        float accv[16];
        #pragma unroll
        for (int e = 0; e < 16; ++e) accv[e] = 0.f;
        for (int s = 0; s < 4; ++s) {
            const u16* pb = partO + ((size_t)(s * 128 + bi)) * 16384
                            + i * 128 + oct * 16;
            u16 a[16];
            *(uint4*)(a)     = *(const uint4*)(pb);
            *(uint4*)(a + 8) = *(const uint4*)(pb + 8);
            #pragma unroll
            for (int e = 0; e < 16; ++e) accv[e] += bf2f(a[e]);
        }
        float fs = fac[il];
        #pragma unroll
        for (int e = 0; e < 16; ++e) accv[e] *= fs;
        uint4 lo = make_uint4(pkbf(accv[0],  accv[1]),  pkbf(accv[2],  accv[3]),
                              pkbf(accv[4],  accv[5]),  pkbf(accv[6],  accv[7]));
        uint4 hi = make_uint4(pkbf(accv[8],  accv[9]),  pkbf(accv[10], accv[11]),
                              pkbf(accv[12], accv[13]), pkbf(accv[14], accv[15]));
        *(uint4*)(h2T + il * 136 + oct * 16)     = lo;
        *(uint4*)(h2T + il * 136 + oct * 16 + 8) = hi;
    }
    __syncthreads();

    floatx4 acc[2][2];
    #pragma unroll
    for (int j = 0; j < 2; ++j) { acc[j][0] = (floatx4)0.f; acc[j][1] = (floatx4)0.f; }
    #pragma unroll
    for (int nt = 0; nt < 2; ++nt)
        #pragma unroll
        for (int kt = 0; kt < 4; ++kt) {
            short8 hf = *(const short8*)(h2T + (nt * 16 + l15) * 136 + kt * 32 + quad * 8);
            acc[0][nt] = mfma16(wf[0][kt], hf, acc[0][nt]);
            acc[1][nt] = mfma16(wf[1][kt], hf, acc[1][nt]);
        }

    int n_base = iblk * 128 + i_base;
    #pragma unroll
    for (int j = 0; j < 2; ++j)
        #pragma unroll
        for (int r = 0; r < 4; ++r) {
            int o = w * 32 + j * 16 + quad * 4 + r;
            float bo = b_out[o];
            #pragma unroll
            for (int nt = 0; nt < 2; ++nt) {
                int n = n_base + nt * 16 + l15;
                size_t idx = ((size_t)(b * 128 + o)) * SEQ + n;
                out[idx] = acc[j][nt][r] + bo + x[idx];
            }
        }
}

// ---------------- launch -------------------------------------------------------
extern "C" void kernel_launch(void* const* d_in, const int* in_sizes, int n_in,
                              void* d_out, int out_size, void* d_ws, size_t ws_size,
                              hipStream_t stream) {
    const float* x     = (const float*)d_in[0];
    const float* gn_w  = (const float*)d_in[1];
    const float* gn_b  = (const float*)d_in[2];
    const float* w_qkv = (const float*)d_in[3];
    const float* b_qkv = (const float*)d_in[4];
    const float* w_out = (const float*)d_in[5];
    const float* b_out = (const float*)d_in[6];
    float* out = (float*)d_out;

    char* ws = (char*)d_ws;
    float* part = (float*)ws;                  //   2 KB @ 0
    u16*  wq  = (u16*)(ws + 4096);             //  96 KB
    u16*  wo  = (u16*)(ws + 102400);           //  32 KB
    u16*  qT  = (u16*)(ws + 135168);           //   4 MB [b][n][c]
    u16*  kT  = (u16*)(ws + 4329472);          //   4 MB [b][n][c]
    u16*  v   = (u16*)(ws + 8523776);          //   4 MB [b][c][n]
    u16*  pO  = (u16*)(ws + 12718080);         //  16 MB partials [js][bi][i][c]
    float* lb = (float*)(ws + 29495296);       // 256 KB
    // total ~29.8 MB

    gn_wconv<<<320, 256, 0, stream>>>(x, part, w_qkv, w_out, wq, wo);
    qkv_fused<<<512, 256, 0, stream>>>(x, gn_w, gn_b, part, wq, b_qkv, qT, kT, v);
    flash_attn<<<512, 256, 0, stream>>>(qT, kT, v, pO, lb);
    merge_out<<<512, 256, 0, stream>>>(pO, lb, wo, b_out, x, out);
}